// Round 1
// baseline (323.200 us; speedup 1.0000x reference)
//
#include <hip/hip_runtime.h>

typedef float  f32x4 __attribute__((ext_vector_type(4)));
typedef short  s16x8 __attribute__((ext_vector_type(8)));
typedef unsigned short u16;

#define HDIM 1024
#define BATCH 32
#define SEQ 2048
#define NROWS (BATCH*SEQ)   // 65536

#define BM 128
#define BN 128
#define BK 32
#define LDK 40              // bf16 elems per LDS row: 32 + 8 pad (80B stride, 16B-aligned)
#define NKT (HDIM/BK)       // 32

__device__ __forceinline__ u16 f2bf(float f){
    unsigned u = __float_as_uint(f);
    u = u + 0x7FFFu + ((u >> 16) & 1u);   // RNE
    return (u16)(u >> 16);
}

__device__ __forceinline__ float tanh_fast(float x){
    // tanh(x) = 1 - 2/(exp2(2*log2e*x)+1); exact at +-inf, ~1ulp elsewhere
    float e = __builtin_amdgcn_exp2f(x * 2.885390082f);
    return 1.0f - 2.0f * __builtin_amdgcn_rcpf(e + 1.0f);
}

// ---------------- W1 -> W1T (bf16, transposed so B-frags are contiguous in k) ----
__global__ __launch_bounds__(256) void k_w1t(const float* __restrict__ W1,
                                             u16* __restrict__ W1T){
    __shared__ u16 t[64][65];
    int blk = blockIdx.x;
    int bh = blk >> 4, bd = blk & 15;     // 16x16 tiles of 64x64
    int h0 = bh * 64, d0 = bd * 64;
    int tid = threadIdx.x;
    int lh = tid >> 4, ld = (tid & 15) * 4;
#pragma unroll
    for (int i = 0; i < 4; ++i){
        int hh = lh + i * 16;
        f32x4 v = *(const f32x4*)&W1[(size_t)(h0 + hh) * HDIM + d0 + ld];
        t[hh][ld + 0] = f2bf(v.x);
        t[hh][ld + 1] = f2bf(v.y);
        t[hh][ld + 2] = f2bf(v.z);
        t[hh][ld + 3] = f2bf(v.w);
    }
    __syncthreads();
    int wv = tid >> 6, ln = tid & 63;
#pragma unroll
    for (int i = 0; i < 16; ++i){
        int d = i * 4 + wv;
        W1T[(size_t)(d0 + d) * HDIM + h0 + ln] = t[ln][d];
    }
}

// ---------------- qproj[b][d] = sum_h query[b][h] * W2[h][d]  (fp32) -------------
__global__ __launch_bounds__(256) void k_qproj(const float* __restrict__ query,
                                               const float* __restrict__ W2,
                                               float* __restrict__ qproj){
    int blk = blockIdx.x;
    int b = blk >> 2, dc = blk & 3;
    int d = dc * 256 + threadIdx.x;
    const float* q = query + (size_t)b * HDIM;
    float acc = 0.f;
#pragma unroll 8
    for (int h = 0; h < HDIM; ++h)
        acc += q[h] * W2[(size_t)h * HDIM + d];
    qproj[(size_t)b * HDIM + d] = acc;
}

// ---------------- fused scores GEMM: spart[row][nt*2+wc] partials ----------------
__global__ __launch_bounds__(256, 2) void k_score(const float* __restrict__ keys,
                                                  const u16*  __restrict__ W1T,
                                                  const float* __restrict__ qproj,
                                                  const float* __restrict__ V,
                                                  float* __restrict__ spart){
    // XCD swizzle: 4096 = 8 XCD * 512; group the 8 n-tiles of an m-tile on one XCD
    int bid  = blockIdx.x;
    int lid  = (bid & 7) * 512 + (bid >> 3);
    int mt   = lid >> 3;          // 0..511
    int nt   = lid & 7;           // 0..7

    __shared__ u16 As[2][BM * LDK];
    __shared__ u16 Bs[2][BM * LDK];

    int tid  = threadIdx.x;
    int wave = tid >> 6, lane = tid & 63;
    int wr = wave >> 1, wc = wave & 1;
    int g  = lane >> 4, q = lane & 15;

    // staging coords: 2 threads per row, 16 elems each
    int srow = tid >> 1;
    int scol = (tid & 1) * 16;
    const float* Aptr = keys + (size_t)(mt * BM + srow) * HDIM + scol;
    const u16*   Bptr = W1T  + (size_t)(nt * BN + srow) * HDIM + scol;

    f32x4 ar[4];
    s16x8 br[2];
    f32x4 acc[4][4];
#pragma unroll
    for (int m = 0; m < 4; ++m)
#pragma unroll
        for (int n = 0; n < 4; ++n) acc[m][n] = 0.f;

    auto load_tile = [&](int kt){
        const float* ap = Aptr + kt * BK;
        ar[0] = *(const f32x4*)(ap + 0);
        ar[1] = *(const f32x4*)(ap + 4);
        ar[2] = *(const f32x4*)(ap + 8);
        ar[3] = *(const f32x4*)(ap + 12);
        const u16* bp = Bptr + kt * BK;
        br[0] = *(const s16x8*)(bp + 0);
        br[1] = *(const s16x8*)(bp + 8);
    };
    auto store_tile = [&](int buf){
        s16x8 p0, p1;
        p0[0]=f2bf(ar[0].x); p0[1]=f2bf(ar[0].y); p0[2]=f2bf(ar[0].z); p0[3]=f2bf(ar[0].w);
        p0[4]=f2bf(ar[1].x); p0[5]=f2bf(ar[1].y); p0[6]=f2bf(ar[1].z); p0[7]=f2bf(ar[1].w);
        p1[0]=f2bf(ar[2].x); p1[1]=f2bf(ar[2].y); p1[2]=f2bf(ar[2].z); p1[3]=f2bf(ar[2].w);
        p1[4]=f2bf(ar[3].x); p1[5]=f2bf(ar[3].y); p1[6]=f2bf(ar[3].z); p1[7]=f2bf(ar[3].w);
        int o = srow * LDK + scol;
        *(s16x8*)&As[buf][o + 0] = p0;
        *(s16x8*)&As[buf][o + 8] = p1;
        *(s16x8*)&Bs[buf][o + 0] = br[0];
        *(s16x8*)&Bs[buf][o + 8] = br[1];
    };

    load_tile(0);
    store_tile(0);
    int cur = 0;
    int abase = (wr * 64 + q) * LDK + g * 8;
    int bbase = (wc * 64 + q) * LDK + g * 8;

    for (int kt = 0; kt < NKT; ++kt){
        if (kt + 1 < NKT) load_tile(kt + 1);
        __syncthreads();
        s16x8 af[4], bq[4];
#pragma unroll
        for (int m = 0; m < 4; ++m) af[m] = *(const s16x8*)&As[cur][abase + m * 16 * LDK];
#pragma unroll
        for (int n = 0; n < 4; ++n) bq[n] = *(const s16x8*)&Bs[cur][bbase + n * 16 * LDK];
#pragma unroll
        for (int m = 0; m < 4; ++m)
#pragma unroll
            for (int n = 0; n < 4; ++n)
                acc[m][n] = __builtin_amdgcn_mfma_f32_16x16x32_bf16(af[m], bq[n], acc[m][n], 0, 0, 0);
        if (kt + 1 < NKT) store_tile(cur ^ 1);
        cur ^= 1;
    }

    // epilogue: score partial = sum_d V[d]*tanh(proj + qproj[b][d]) over this block's 64 cols
    int b_idx = mt >> 4;   // 2048 rows per batch = 16 m-tiles
    float Vn[4], Qn[4];
#pragma unroll
    for (int n = 0; n < 4; ++n){
        int D = nt * BN + wc * 64 + n * 16 + q;
        Vn[n] = V[D];
        Qn[n] = qproj[(size_t)b_idx * HDIM + D];
    }
#pragma unroll
    for (int m = 0; m < 4; ++m){
#pragma unroll
        for (int r = 0; r < 4; ++r){
            float s = 0.f;
#pragma unroll
            for (int n = 0; n < 4; ++n){
                float x = acc[m][n][r] + Qn[n];
                s += Vn[n] * tanh_fast(x);
            }
            s += __shfl_xor(s, 1);
            s += __shfl_xor(s, 2);
            s += __shfl_xor(s, 4);
            s += __shfl_xor(s, 8);
            if (q == 0){
                int R = mt * BM + wr * 64 + m * 16 + g * 4 + r;
                spart[(size_t)R * 16 + nt * 2 + wc] = s;
            }
        }
    }
}

// ---------------- softmax over S per batch ---------------------------------------
__global__ __launch_bounds__(256) void k_softmax(const float* __restrict__ spart,
                                                 const int* __restrict__ mask,
                                                 float* __restrict__ attn){
    int b = blockIdx.x;
    int tid = threadIdx.x;
    int lane = tid & 63, wv = tid >> 6;
    __shared__ float redmx[4];
    __shared__ float redsm[4];

    float sc[8];
#pragma unroll
    for (int i = 0; i < 8; ++i){
        int s = i * 256 + tid;
        const f32x4* p = (const f32x4*)&spart[(size_t)(b * SEQ + s) * 16];
        f32x4 v0 = p[0], v1 = p[1], v2 = p[2], v3 = p[3];
        float sum = (v0.x + v0.y + v0.z + v0.w) + (v1.x + v1.y + v1.z + v1.w)
                  + (v2.x + v2.y + v2.z + v2.w) + (v3.x + v3.y + v3.z + v3.w);
        sc[i] = (mask[b * SEQ + s] == 0) ? -1e9f : sum;
    }
    float mx = sc[0];
#pragma unroll
    for (int i = 1; i < 8; ++i) mx = fmaxf(mx, sc[i]);
#pragma unroll
    for (int o = 32; o >= 1; o >>= 1) mx = fmaxf(mx, __shfl_xor(mx, o));
    if (lane == 0) redmx[wv] = mx;
    __syncthreads();
    mx = fmaxf(fmaxf(redmx[0], redmx[1]), fmaxf(redmx[2], redmx[3]));

    float ex[8], ssum = 0.f;
#pragma unroll
    for (int i = 0; i < 8; ++i){
        ex[i] = __builtin_amdgcn_exp2f((sc[i] - mx) * 1.4426950408889634f);
        ssum += ex[i];
    }
#pragma unroll
    for (int o = 32; o >= 1; o >>= 1) ssum += __shfl_xor(ssum, o);
    if (lane == 0) redsm[wv] = ssum;
    __syncthreads();
    ssum = redsm[0] + redsm[1] + redsm[2] + redsm[3];
    float inv = 1.0f / ssum;
#pragma unroll
    for (int i = 0; i < 8; ++i)
        attn[(size_t)b * SEQ + i * 256 + tid] = ex[i] * inv;
}

// ---------------- context partials: cpart[b][sc][h] ------------------------------
__global__ __launch_bounds__(256) void k_ctxpart(const float* __restrict__ keys,
                                                 const float* __restrict__ attn,
                                                 float* __restrict__ cpart){
    int blk = blockIdx.x;
    int b = blk >> 4, scn = blk & 15;
    int tid = threadIdx.x;
    f32x4 acc = 0.f;
    const f32x4* kp = (const f32x4*)(keys + (size_t)(b * SEQ + scn * 128) * HDIM) + tid;
    const float* ap = attn + (size_t)b * SEQ + scn * 128;
#pragma unroll 4
    for (int s = 0; s < 128; ++s){
        float a = ap[s];
        acc += a * kp[(size_t)s * 256];
    }
    *(f32x4*)&cpart[(size_t)(b * 16 + scn) * HDIM + tid * 4] = acc;
}

__global__ __launch_bounds__(256) void k_ctxred(const float* __restrict__ cpart,
                                                float* __restrict__ ctx){
    int idx = blockIdx.x * 256 + threadIdx.x;   // 0..32767
    int b = idx >> 10, h = idx & 1023;
    float s = 0.f;
#pragma unroll
    for (int sc = 0; sc < 16; ++sc)
        s += cpart[(size_t)(b * 16 + sc) * HDIM + h];
    ctx[idx] = s;
}

// ---------------- launch ---------------------------------------------------------
extern "C" void kernel_launch(void* const* d_in, const int* in_sizes, int n_in,
                              void* d_out, int out_size, void* d_ws, size_t ws_size,
                              hipStream_t stream){
    (void)in_sizes; (void)n_in; (void)out_size; (void)ws_size;
    const float* query = (const float*)d_in[0];
    const float* keys  = (const float*)d_in[1];
    const int*   mask  = (const int*)d_in[2];
    const float* W1    = (const float*)d_in[3];
    const float* W2    = (const float*)d_in[4];
    const float* V     = (const float*)d_in[5];

    float* ctx_out  = (float*)d_out;            // [32][1024]
    float* attn_out = ctx_out + BATCH * HDIM;   // [32][2048]

    char* ws = (char*)d_ws;
    u16*   W1T   = (u16*)ws;                                   // 2 MB
    float* qproj = (float*)(ws + (2u << 20));                  // 128 KB
    float* spart = (float*)(ws + (2u << 20) + (128u << 10));   // 4 MB
    float* cpart = (float*)(ws + (6u << 20) + (128u << 10));   // 2 MB

    k_w1t    <<<dim3(256),  dim3(256), 0, stream>>>(W1, W1T);
    k_qproj  <<<dim3(128),  dim3(256), 0, stream>>>(query, W2, qproj);
    k_score  <<<dim3(4096), dim3(256), 0, stream>>>(keys, W1T, qproj, V, spart);
    k_softmax<<<dim3(32),   dim3(256), 0, stream>>>(spart, mask, attn_out);
    k_ctxpart<<<dim3(512),  dim3(256), 0, stream>>>(keys, attn_out, cpart);
    k_ctxred <<<dim3(128),  dim3(256), 0, stream>>>(cpart, ctx_out);
}